// Round 19
// baseline (205.053 us; speedup 1.0000x reference)
//
#include <hip/hip_runtime.h>
#include <hip/hip_cooperative_groups.h>

namespace cg = cooperative_groups;

#define B_ 32
#define T_ 64
#define I_ 256
#define H_ 512

static constexpr float ALPHA_F = 0.951229424500714f;   // exp(-1/20)
static constexpr float OMD_F   = 0.048770575499286f;   // 1 - decay
static constexpr float ETA_F   = 0.1f;
static constexpr float CSCALE  = 0.02f;                // 0.2 * ETA

typedef __bf16 bf16x8 __attribute__((ext_vector_type(8)));
typedef float  f32x4  __attribute__((ext_vector_type(4)));

// ---------------- helpers ----------------
__device__ __forceinline__ float tanh_fast(float x) {
  float xc = fminf(fmaxf(x, -15.f), 15.f);
  float e = __expf(2.f * xc);
  return (e - 1.f) * __builtin_amdgcn_rcpf(e + 1.f);
}
__device__ __forceinline__ unsigned int f2bf(float f) {   // RNE, low 16 bits
  unsigned int u = __float_as_uint(f);
  u += 0x7fffu + ((u >> 16) & 1u);
  return u >> 16;
}
// split fp32x8 -> (hi, lo) bf16x8 pair: v ~= hi + lo, ~17 mantissa bits
__device__ __forceinline__ void split8(const float* p, bf16x8& hi, bf16x8& lo) {
  float4 f0 = *reinterpret_cast<const float4*>(p);
  float4 f1 = *reinterpret_cast<const float4*>(p + 4);
  float f[8] = {f0.x, f0.y, f0.z, f0.w, f1.x, f1.y, f1.z, f1.w};
#pragma unroll
  for (int i = 0; i < 8; ++i) {
    __bf16 h = (__bf16)f[i];
    hi[i] = h;
    lo[i] = (__bf16)(f[i] - (float)h);
  }
}

template <int CTRL>
__device__ __forceinline__ float dpp_add(float x) {
  int mv = __builtin_amdgcn_update_dpp(0, __float_as_int(x), CTRL, 0xF, 0xF, true);
  return x + __int_as_float(mv);
}
__device__ __forceinline__ float wave_sum_dpp(float x) {
  x = dpp_add<0x111>(x);
  x = dpp_add<0x112>(x);
  x = dpp_add<0x114>(x);
  x = dpp_add<0x118>(x);
  x = dpp_add<0x142>(x);
  x = dpp_add<0x143>(x);   // lane63 = full 64-lane sum
  return x;
}

// ---------------- vscan macros (R14 body, Cs from smem row-stride 64) ----------------
#define CSP(t) (smem + ((t) << 6))
#define IVG(T) (((T) & 3) == 0 ? ivq[(T) >> 2].x : ((T) & 3) == 1 ? ivq[(T) >> 2].y \
              : ((T) & 3) == 2 ? ivq[(T) >> 2].z : ivq[(T) >> 2].w)
#define VQSET(T, val) do { \
    if (((T) & 3) == 0)      vqv[(T) >> 2].x = (val); \
    else if (((T) & 3) == 1) vqv[(T) >> 2].y = (val); \
    else if (((T) & 3) == 2) vqv[(T) >> 2].z = (val); \
    else                     vqv[(T) >> 2].w = (val); } while (0)

#define VSTEP(TT, CUR, NXT)                                                   \
  {                                                                           \
    if ((TT) + 1 < T_) {                                                      \
      _Pragma("unroll")                                                       \
      for (int q = 0; q < 16; ++q)                                            \
        NXT[q] = *reinterpret_cast<const float4*>(CSP((TT) + 1) + 4 * q);     \
    }                                                                         \
    float p0 = 0.f, p1 = 0.f, p2 = 0.f, p3 = 0.f;                             \
    _Pragma("unroll")                                                         \
    for (int q = 0; q < 16; ++q) {                                            \
      p0 += CUR[q].x * vqv[q].x;                                              \
      p1 += CUR[q].y * vqv[q].y;                                              \
      p2 += CUR[q].z * vqv[q].z;                                              \
      p3 += CUR[q].w * vqv[q].w;                                              \
    }                                                                         \
    float ikv = (p0 + p1) + (p2 + p3);                                        \
    vv = ALPHA_F * vv + IVG(TT) + ikv;                                        \
    float v = tanh_fast(vv);                                                  \
    vt = ALPHA_F * vt + OMD_F * v;                                            \
    VQSET(TT, vt);                                                            \
    vo[(size_t)(TT) * H_] = v;                                                \
  }

#define VP2(T2) VSTEP(T2, ca, cbuf) VSTEP((T2) + 1, cbuf, ca)
#define VP8(T8) VP2(T8) VP2((T8) + 2) VP2((T8) + 4) VP2((T8) + 6)
#define IVLD(Q) { ivq[Q].x = pv[(size_t)(4 * (Q) + 0) * H_]; \
                  ivq[Q].y = pv[(size_t)(4 * (Q) + 1) * H_]; \
                  ivq[Q].z = pv[(size_t)(4 * (Q) + 2) * H_]; \
                  ivq[Q].w = pv[(size_t)(4 * (Q) + 3) * H_]; }

// ====== Fused cooperative kernel: proj+kscan | dots | vscan | mem ======
__global__ __launch_bounds__(256, 1) void fused_kernel(
    const float* __restrict__ x, const float* __restrict__ W,
    float* __restrict__ keys, float* __restrict__ ktg,
    ushort* __restrict__ ktb16T, float* __restrict__ ivbuf,
    float* __restrict__ vals, ushort* __restrict__ vtb16T,
    float* __restrict__ Cbuf, float* __restrict__ mem) {
  cg::grid_group grid = cg::this_grid();
  __shared__ __align__(16) float smem[64 * 68];   // proj scr (64x68) / vscan Cs (64x64)
  const int g = blockIdx.x;
  const int tid = threadIdx.x;
  const int w = tid >> 6, l = tid & 63;
  const int lrow = l & 15, lk8 = (l >> 4) * 8;
  const int tr0 = (l >> 4) * 4, tc = lrow;

  // ===== Phase A: proj (split-precision MFMA) + fused kscan; tasks g, g+256 =====
#pragma unroll
  for (int it = 0; it < 2; ++it) {
    const int tau = g + it * 256;
    const int b  = tau >> 4;
    const int n0 = (tau & 15) * 64;
    const int m0 = b * 64;
    __syncthreads();   // smem reuse across tasks
    const float* xr = x + (size_t)(m0 + w * 16 + lrow) * I_ + lk8;
    const float* wr = W + (size_t)(n0 + lrow) * I_ + lk8;
    f32x4 acc[4] = {};
#pragma unroll
    for (int ks = 0; ks < 8; ++ks) {
      bf16x8 ah, al;
      split8(xr + ks * 32, ah, al);
#pragma unroll
      for (int jt = 0; jt < 4; ++jt) {
        bf16x8 bh, bl;
        split8(wr + (size_t)jt * 16 * I_ + ks * 32, bh, bl);
        acc[jt] = __builtin_amdgcn_mfma_f32_16x16x32_bf16(ah, bh, acc[jt], 0, 0, 0);
        acc[jt] = __builtin_amdgcn_mfma_f32_16x16x32_bf16(al, bh, acc[jt], 0, 0, 0);
        acc[jt] = __builtin_amdgcn_mfma_f32_16x16x32_bf16(ah, bl, acc[jt], 0, 0, 0);
      }
    }
    if (n0 < 512) {
#pragma unroll
      for (int jt = 0; jt < 4; ++jt)
#pragma unroll
        for (int r = 0; r < 4; ++r)
          smem[(w * 16 + tr0 + r) * 68 + jt * 16 + tc] = acc[jt][r];
      __syncthreads();
      if (tid < 64) {
        float kv = 0.f, kt = 0.f;
        unsigned int kpk[32];
        float* ko  = keys + (size_t)b * T_ * H_ + n0 + tid;
        float* kto = ktg  + (size_t)b * T_ * H_ + n0 + tid;
#pragma unroll
        for (int t = 0; t < T_; ++t) {
          kv = ALPHA_F * kv + smem[t * 68 + tid];
          float k = tanh_fast(kv);
          kt = ALPHA_F * kt + OMD_F * k;
          ko[(size_t)t * H_]  = k;
          kto[(size_t)t * H_] = kt;
          unsigned int us = f2bf(kt);
          if ((t & 1) == 0) kpk[t >> 1] = us;
          else              kpk[t >> 1] |= us << 16;
        }
        ushort* kb = ktb16T + ((size_t)b * H_ + n0 + tid) * T_;
#pragma unroll
        for (int e = 0; e < 8; ++e)
          reinterpret_cast<uint4*>(kb)[e] =
              make_uint4(kpk[4 * e], kpk[4 * e + 1], kpk[4 * e + 2], kpk[4 * e + 3]);
      }
    } else {
      const int hv0 = n0 - 512;
#pragma unroll
      for (int jt = 0; jt < 4; ++jt)
#pragma unroll
        for (int r = 0; r < 4; ++r)
          ivbuf[((size_t)b * T_ + w * 16 + tr0 + r) * H_ + hv0 + jt * 16 + tc] = acc[jt][r];
    }
  }
  grid.sync();

  // ===== Phase B: dots — C[b][t][s] = 0.02 * (k_t . kt_s); 2 wave-tasks =====
#pragma unroll
  for (int it = 0; it < 2; ++it) {
    const int task = it * 1024 + g * 4 + w;
    const int b = task >> 6, t = task & 63;
    const float* krow = keys + ((size_t)b * T_ + t) * H_ + 4 * l;
    float4 k0 = *reinterpret_cast<const float4*>(krow);
    float4 k1 = *reinterpret_cast<const float4*>(krow + 256);
    const float* tb = ktg + (size_t)b * T_ * H_ + 4 * l;
    float* Cb = Cbuf + ((size_t)b * T_ + t) * T_;
#pragma unroll 8
    for (int s = 0; s < T_; ++s) {
      const float* ar = tb + (size_t)s * H_;
      float4 a0 = *reinterpret_cast<const float4*>(ar);
      float4 a1 = *reinterpret_cast<const float4*>(ar + 256);
      float p = a0.x * k0.x + a0.y * k0.y + a0.z * k0.z + a0.w * k0.w
              + a1.x * k1.x + a1.y * k1.y + a1.z * k1.z + a1.w * k1.w;
      p = wave_sum_dpp(p);
      if (l == 63) Cb[s] = CSCALE * p;
    }
  }
  grid.sync();

  // ===== Phase C: v-scan — blocks 0..63, one (b,hblock) task per wave =====
  if (g < 64) {
    const int b = g >> 1;
#pragma unroll
    for (int e = 0; e < 4; ++e)
      reinterpret_cast<float4*>(smem)[tid + (e << 8)] =
          reinterpret_cast<const float4*>(Cbuf + (size_t)b * T_ * T_)[tid + (e << 8)];
    __syncthreads();

    const int hb = ((g & 1) << 2) + w;
    const int h  = (hb << 6) + l;
    const float* pv = ivbuf + (size_t)b * T_ * H_ + h;
    float* vo = vals + ((size_t)b * T_) * H_ + h;

    float4 ivq[16];
    IVLD(0)  IVLD(1)  IVLD(2)  IVLD(3)  IVLD(4)  IVLD(5)  IVLD(6)  IVLD(7)
    IVLD(8)  IVLD(9)  IVLD(10) IVLD(11) IVLD(12) IVLD(13) IVLD(14) IVLD(15)

    float vv = 0.f, vt = 0.f;
    float4 vqv[16];
#pragma unroll
    for (int q = 0; q < 16; ++q) vqv[q] = make_float4(0.f, 0.f, 0.f, 0.f);

    float4 ca[16], cbuf[16];
#pragma unroll
    for (int q = 0; q < 16; ++q)
      ca[q] = *reinterpret_cast<const float4*>(CSP(0) + 4 * q);

    VP8(0) VP8(8) VP8(16) VP8(24) VP8(32) VP8(40) VP8(48) VP8(56)

    // vt history -> bf16 [h][t], 128 B contiguous per thread
    ushort* vb16 = vtb16T + ((size_t)b * H_ + h) * T_;
#pragma unroll
    for (int q = 0; q < 16; ++q) {
      unsigned int u0 = f2bf(vqv[q].x) | (f2bf(vqv[q].y) << 16);
      unsigned int u1 = f2bf(vqv[q].z) | (f2bf(vqv[q].w) << 16);
      reinterpret_cast<uint2*>(vb16)[q] = make_uint2(u0, u1);
    }
  }
  grid.sync();

  // ===== Phase D: mem = ETA * vt^T @ kt via MFMA; 8 tile-tasks per block =====
#pragma unroll
  for (int it = 0; it < 8; ++it) {
    const int task = it * 256 + g;
    const int b   = task >> 6;
    const int rem = task & 63;
    const int i0 = (rem >> 3) << 6;
    const int j0 = (rem & 7) << 6;
    const ushort* ar = vtb16T + ((size_t)b * H_ + i0 + w * 16 + lrow) * T_ + lk8;
    const ushort* br = ktb16T + ((size_t)b * H_ + j0 + lrow) * T_ + lk8;
    f32x4 acc[4] = {};
#pragma unroll
    for (int ks = 0; ks < 2; ++ks) {
      bf16x8 a = *reinterpret_cast<const bf16x8*>(ar + ks * 32);
#pragma unroll
      for (int jt = 0; jt < 4; ++jt) {
        bf16x8 bv = *reinterpret_cast<const bf16x8*>(br + (size_t)jt * 16 * T_ + ks * 32);
        acc[jt] = __builtin_amdgcn_mfma_f32_16x16x32_bf16(a, bv, acc[jt], 0, 0, 0);
      }
    }
    float* mb = mem + (size_t)b * H_ * H_;
#pragma unroll
    for (int jt = 0; jt < 4; ++jt)
#pragma unroll
      for (int r = 0; r < 4; ++r)
        mb[((size_t)i0 + w * 16 + tr0 + r) * H_ + j0 + jt * 16 + tc] = ETA_F * acc[jt][r];
  }
}

extern "C" void kernel_launch(void* const* d_in, const int* in_sizes, int n_in,
                              void* d_out, int out_size, void* d_ws, size_t ws_size,
                              hipStream_t stream) {
  const float* x = (const float*)d_in[0];   // (B,T,I)
  const float* W = (const float*)d_in[1];   // (2H,I)
  float* out = (float*)d_out;
  float* mem  = out;
  float* keys = out + (size_t)B_ * H_ * H_;
  float* vals = keys + (size_t)B_ * T_ * H_;

  // d_ws: ktg 4MB | ivbuf 4MB | ktb16T 2MB | vtb16T 2MB | Cbuf 0.5MB
  float*  ktg    = (float*)d_ws;
  float*  ivbuf  = ktg + (size_t)B_ * T_ * H_;
  ushort* ktb16T = (ushort*)(ivbuf + (size_t)B_ * T_ * H_);
  ushort* vtb16T = ktb16T + (size_t)B_ * H_ * T_;
  float*  Cbuf   = (float*)(vtb16T + (size_t)B_ * H_ * T_);

  void* kargs[] = {(void*)&x, (void*)&W, (void*)&keys, (void*)&ktg, (void*)&ktb16T,
                   (void*)&ivbuf, (void*)&vals, (void*)&vtb16T, (void*)&Cbuf, (void*)&mem};
  (void)hipLaunchCooperativeKernel((const void*)fused_kernel, dim3(256), dim3(256),
                                   kargs, 0, stream);
}

// Round 20
// 87.000 us; speedup vs baseline: 2.3569x; 2.3569x over previous
//
#include <hip/hip_runtime.h>

#define B_ 32
#define T_ 64
#define I_ 256
#define H_ 512

static constexpr float ALPHA_F = 0.951229424500714f;   // exp(-1/20)
static constexpr float OMD_F   = 0.048770575499286f;   // 1 - decay
static constexpr float ETA_F   = 0.1f;
static constexpr float CSCALE  = 0.02f;                // 0.2 * ETA

// ---------------- fast tanh ----------------
__device__ __forceinline__ float tanh_fast(float x) {
  float xc = fminf(fmaxf(x, -15.f), 15.f);
  float e = __expf(2.f * xc);
  return (e - 1.f) * __builtin_amdgcn_rcpf(e + 1.f);
}

// ---------------- DPP full-wave sum; result in lane 63 ----------------
template <int CTRL>
__device__ __forceinline__ float dpp_add(float x) {
  int mv = __builtin_amdgcn_update_dpp(0, __float_as_int(x), CTRL, 0xF, 0xF, true);
  return x + __int_as_float(mv);
}
__device__ __forceinline__ float wave_sum_dpp(float x) {
  x = dpp_add<0x111>(x);
  x = dpp_add<0x112>(x);
  x = dpp_add<0x114>(x);
  x = dpp_add<0x118>(x);
  x = dpp_add<0x142>(x);
  x = dpp_add<0x143>(x);
  return x;
}

// ====== Kernel 1: projection GEMM (k-major LDS, b128 frags) + fused k-scan ======
// m-tile == one batch (m = b*64 + t). k-half blocks (n0<512) run the k-recurrence
// on their 64 h-columns, writing keys/ktg. v-half writes ivbuf.
__global__ __launch_bounds__(256) void proj_kscan(const float* __restrict__ x,
                                                  const float* __restrict__ W,
                                                  float* __restrict__ keys,
                                                  float* __restrict__ ktg,
                                                  float* __restrict__ ivbuf) {
  __shared__ float Ak[64][68];   // [kk][m], 272B rows (16B-aligned)
  __shared__ float Bk[64][68];   // [kk][n]
  const int b  = blockIdx.x;
  const int n0 = blockIdx.y * 64;
  const int m0 = b * 64;
  const int tid = threadIdx.x;
  const int ty = tid >> 4, tx = tid & 15;
  const int sr = tid >> 2;        // 0..63 (m or n index for staging)
  const int sc = tid & 3;         // base col-quad
  float acc[4][4] = {};

  for (int k0 = 0; k0 < I_; k0 += 64) {
    // stage transposed: float4 global load, 4 scalar LDS writes (2-way conflicts)
#pragma unroll
    for (int e = 0; e < 4; ++e) {
      const int cq = sc + 4 * e;  // 0..15 col-quad
      float4 xv = *reinterpret_cast<const float4*>(&x[(size_t)(m0 + sr) * I_ + k0 + cq * 4]);
      Ak[cq * 4 + 0][sr] = xv.x;
      Ak[cq * 4 + 1][sr] = xv.y;
      Ak[cq * 4 + 2][sr] = xv.z;
      Ak[cq * 4 + 3][sr] = xv.w;
      float4 wv = *reinterpret_cast<const float4*>(&W[(size_t)(n0 + sr) * I_ + k0 + cq * 4]);
      Bk[cq * 4 + 0][sr] = wv.x;
      Bk[cq * 4 + 1][sr] = wv.y;
      Bk[cq * 4 + 2][sr] = wv.z;
      Bk[cq * 4 + 3][sr] = wv.w;
    }
    __syncthreads();
#pragma unroll 8
    for (int kk = 0; kk < 64; ++kk) {
      float4 a4 = *reinterpret_cast<const float4*>(&Ak[kk][ty * 4]);
      float4 b4 = *reinterpret_cast<const float4*>(&Bk[kk][tx * 4]);
      float av[4] = {a4.x, a4.y, a4.z, a4.w};
      float bv[4] = {b4.x, b4.y, b4.z, b4.w};
#pragma unroll
      for (int i = 0; i < 4; ++i)
#pragma unroll
        for (int j = 0; j < 4; ++j) acc[i][j] += av[i] * bv[j];
    }
    __syncthreads();
  }

  if (n0 < 512) {
    // stash acc -> scratch[t][hh] (reuse Ak region), then wave 0 scans columns
    float* scr = &Ak[0][0];
#pragma unroll
    for (int i = 0; i < 4; ++i)
#pragma unroll
      for (int j = 0; j < 4; ++j) scr[(ty * 4 + i) * 68 + tx * 4 + j] = acc[i][j];
    __syncthreads();
    if (tid < 64) {
      float kv = 0.f, kt = 0.f;
      float* ko  = keys + (size_t)b * T_ * H_ + n0 + tid;
      float* kto = ktg  + (size_t)b * T_ * H_ + n0 + tid;
#pragma unroll 8
      for (int t = 0; t < T_; ++t) {
        kv = ALPHA_F * kv + scr[t * 68 + tid];
        float k = tanh_fast(kv);
        kt = ALPHA_F * kt + OMD_F * k;
        ko[(size_t)t * H_]  = k;
        kto[(size_t)t * H_] = kt;
      }
    }
  } else {
    const int hv0 = n0 - 512;
#pragma unroll
    for (int i = 0; i < 4; ++i)
      *reinterpret_cast<float4*>(&ivbuf[((size_t)b * T_ + ty * 4 + i) * H_ + hv0 + tx * 4]) =
          make_float4(acc[i][0], acc[i][1], acc[i][2], acc[i][3]);
  }
}

// ====== Kernel 2: dots — C[b][t][s] = 0.02 * (k_t . kt_s) ======
__global__ __launch_bounds__(512) void dots_kernel(const float* __restrict__ keys,
                                                   const float* __restrict__ ktg,
                                                   float* __restrict__ C) {
  const int b = blockIdx.y;
  const int t = blockIdx.x * 8 + (threadIdx.x >> 6);
  const int lane = threadIdx.x & 63;
  const float* krow = keys + ((size_t)b * T_ + t) * H_ + 4 * lane;
  float4 k0 = *reinterpret_cast<const float4*>(krow);
  float4 k1 = *reinterpret_cast<const float4*>(krow + 256);
  const float* tb = ktg + (size_t)b * T_ * H_ + 4 * lane;
  float* Cb = C + ((size_t)b * T_ + t) * T_;
#pragma unroll 8
  for (int s = 0; s < T_; ++s) {
    const float* ar = tb + (size_t)s * H_;
    float4 a0 = *reinterpret_cast<const float4*>(ar);
    float4 a1 = *reinterpret_cast<const float4*>(ar + 256);
    float p = a0.x * k0.x + a0.y * k0.y + a0.z * k0.z + a0.w * k0.w
            + a1.x * k1.x + a1.y * k1.y + a1.z * k1.z + a1.w * k1.w;
    p = wave_sum_dpp(p);
    if (lane == 63) Cb[s] = CSCALE * p;
  }
}

// ====== Kernel 3: v-side scan — 1 wave/block, fully unrolled, all state in regs ======
#define IVG(T) (((T) & 3) == 0 ? ivq[(T) >> 2].x : ((T) & 3) == 1 ? ivq[(T) >> 2].y \
              : ((T) & 3) == 2 ? ivq[(T) >> 2].z : ivq[(T) >> 2].w)
#define VQSET(T, val) do { \
    if (((T) & 3) == 0)      vqv[(T) >> 2].x = (val); \
    else if (((T) & 3) == 1) vqv[(T) >> 2].y = (val); \
    else if (((T) & 3) == 2) vqv[(T) >> 2].z = (val); \
    else                     vqv[(T) >> 2].w = (val); } while (0)

#define VSTEP(TT, CUR, NXT)                                                   \
  {                                                                           \
    if ((TT) + 1 < T_) {                                                      \
      _Pragma("unroll")                                                       \
      for (int q = 0; q < 16; ++q)                                            \
        NXT[q] = *reinterpret_cast<const float4*>(&Cs[(TT) + 1][4 * q]);      \
    }                                                                         \
    float p0 = 0.f, p1 = 0.f, p2 = 0.f, p3 = 0.f;                             \
    _Pragma("unroll")                                                         \
    for (int q = 0; q < 16; ++q) {                                            \
      p0 += CUR[q].x * vqv[q].x;                                              \
      p1 += CUR[q].y * vqv[q].y;                                              \
      p2 += CUR[q].z * vqv[q].z;                                              \
      p3 += CUR[q].w * vqv[q].w;                                              \
    }                                                                         \
    float ikv = (p0 + p1) + (p2 + p3);                                        \
    vv = ALPHA_F * vv + IVG(TT) + ikv;                                        \
    float v = tanh_fast(vv);                                                  \
    vt = ALPHA_F * vt + OMD_F * v;                                            \
    VQSET(TT, vt);                                                            \
    vo[(size_t)(TT) * H_]  = v;                                               \
    vto[(size_t)(TT) * H_] = vt;                                              \
  }

#define VP2(T2) VSTEP(T2, ca, cbuf) VSTEP((T2) + 1, cbuf, ca)
#define VP8(T8) VP2(T8) VP2((T8) + 2) VP2((T8) + 4) VP2((T8) + 6)
#define IVLD(Q) { ivq[Q].x = pv[(size_t)(4 * (Q) + 0) * H_]; \
                  ivq[Q].y = pv[(size_t)(4 * (Q) + 1) * H_]; \
                  ivq[Q].z = pv[(size_t)(4 * (Q) + 2) * H_]; \
                  ivq[Q].w = pv[(size_t)(4 * (Q) + 3) * H_]; }

__global__ __launch_bounds__(64, 1) void vscan_kernel(const float* __restrict__ ivbuf,
                                                      const float* __restrict__ C,
                                                      float* __restrict__ vals,
                                                      float* __restrict__ vtg) {
  __shared__ float Cs[T_][T_];   // 16 KB
  const int b    = blockIdx.x >> 3;
  const int lane = threadIdx.x;
  const int h    = ((blockIdx.x & 7) << 6) + lane;

  const float* Cb = C + (size_t)b * T_ * T_;
#pragma unroll
  for (int e = 0; e < 16; ++e)
    reinterpret_cast<float4*>(&Cs[0][0])[lane + (e << 6)] =
        reinterpret_cast<const float4*>(Cb)[lane + (e << 6)];

  const float* pv = ivbuf + (size_t)b * T_ * H_ + h;
  float* vo  = vals + ((size_t)b * T_) * H_ + h;
  float* vto = vtg  + ((size_t)b * T_) * H_ + h;

  float4 ivq[16];
  IVLD(0)  IVLD(1)  IVLD(2)  IVLD(3)  IVLD(4)  IVLD(5)  IVLD(6)  IVLD(7)
  IVLD(8)  IVLD(9)  IVLD(10) IVLD(11) IVLD(12) IVLD(13) IVLD(14) IVLD(15)

  float vv = 0.f, vt = 0.f;
  float4 vqv[16];
#pragma unroll
  for (int q = 0; q < 16; ++q) vqv[q] = make_float4(0.f, 0.f, 0.f, 0.f);

  __syncthreads();

  float4 ca[16], cbuf[16];
#pragma unroll
  for (int q = 0; q < 16; ++q)
    ca[q] = *reinterpret_cast<const float4*>(&Cs[0][4 * q]);

  VP8(0) VP8(8) VP8(16) VP8(24) VP8(32) VP8(40) VP8(48) VP8(56)
}

// ====== Kernel 4: mem = ETA * vt^T @ kt — k-major LDS (global already [t][h]), b128 frags ======
__global__ __launch_bounds__(256) void mem_gemm(const float* __restrict__ vtg,
                                                const float* __restrict__ ktg,
                                                float* __restrict__ mem) {
  const int b = blockIdx.z;
  const int i0 = blockIdx.y * 64;
  const int j0 = blockIdx.x * 64;
  __shared__ float Vs[64][68];   // [t][i], 272B rows
  __shared__ float Ks[64][68];   // [t][j]
  const int tid = threadIdx.x;
  const int ty = tid >> 4, tx = tid & 15;
  const float* vb = vtg + (size_t)b * T_ * H_;
  const float* kb = ktg + (size_t)b * T_ * H_;
#pragma unroll
  for (int e = 0; e < 16; ++e) {
    int idx = tid + e * 256;
    int t = idx >> 6, c = idx & 63;
    Vs[t][c] = vb[(size_t)t * H_ + i0 + c];
    Ks[t][c] = kb[(size_t)t * H_ + j0 + c];
  }
  __syncthreads();
  float acc[4][4] = {};
#pragma unroll 8
  for (int t = 0; t < 64; ++t) {
    float4 a4 = *reinterpret_cast<const float4*>(&Vs[t][ty * 4]);
    float4 b4 = *reinterpret_cast<const float4*>(&Ks[t][tx * 4]);
    float av[4] = {a4.x, a4.y, a4.z, a4.w};
    float bv[4] = {b4.x, b4.y, b4.z, b4.w};
#pragma unroll
    for (int i = 0; i < 4; ++i)
#pragma unroll
      for (int j = 0; j < 4; ++j) acc[i][j] += av[i] * bv[j];
  }
  float* mb = mem + (size_t)b * H_ * H_;
#pragma unroll
  for (int i = 0; i < 4; ++i) {
    float4 o = make_float4(ETA_F * acc[i][0], ETA_F * acc[i][1],
                           ETA_F * acc[i][2], ETA_F * acc[i][3]);
    *reinterpret_cast<float4*>(&mb[(size_t)(i0 + ty * 4 + i) * H_ + j0 + tx * 4]) = o;
  }
}

extern "C" void kernel_launch(void* const* d_in, const int* in_sizes, int n_in,
                              void* d_out, int out_size, void* d_ws, size_t ws_size,
                              hipStream_t stream) {
  const float* x = (const float*)d_in[0];   // (B,T,I)
  const float* W = (const float*)d_in[1];   // (2H,I)
  float* out = (float*)d_out;
  float* mem  = out;
  float* keys = out + (size_t)B_ * H_ * H_;
  float* vals = keys + (size_t)B_ * T_ * H_;

  // scratch in d_ws: ktg 4MB | ivbuf 4MB | vtg 4MB | C 0.5MB
  float* ktg   = (float*)d_ws;
  float* ivbuf = ktg + (size_t)B_ * T_ * H_;
  float* vtg   = ivbuf + (size_t)B_ * T_ * H_;
  float* Cbuf  = vtg + (size_t)B_ * T_ * H_;

  proj_kscan<<<dim3(B_, 16), 256, 0, stream>>>(x, W, keys, ktg, ivbuf);
  dots_kernel<<<dim3(8, B_), 512, 0, stream>>>(keys, ktg, Cbuf);
  vscan_kernel<<<dim3(8 * B_), 64, 0, stream>>>(ivbuf, Cbuf, vals, vtg);
  mem_gemm<<<dim3(8, 8, B_), 256, 0, stream>>>(vtg, ktg, mem);
}